// Round 11
// baseline (614.701 us; speedup 1.0000x reference)
//
#include <hip/hip_runtime.h>
#include <math.h>

#define N_NODES 102400
#define N_EDGES 1638400
#define G_GRAPHS 256
#define F_IN  64
#define H1    4
#define C1    32
#define F_MID 128
#define C2    32
#define CLIN  5
#define NEG   0.2f
#define NODES_PER_G 400

__device__ __forceinline__ float lrelu(float x) { return x > 0.f ? x : NEG * x; }
__device__ __forceinline__ float elu(float x)   { return x > 0.f ? x : expm1f(x); }

__device__ __forceinline__ unsigned short f2bf(float f) {
    unsigned u = __float_as_uint(f);
    u = (u + 0x7fffu + ((u >> 16) & 1u)) >> 16;
    return (unsigned short)u;
}
__device__ __forceinline__ float4 bf2f4(uint2 p) {
    return make_float4(__uint_as_float(p.x << 16), __uint_as_float(p.x & 0xffff0000u),
                       __uint_as_float(p.y << 16), __uint_as_float(p.y & 0xffff0000u));
}

// ---------------- CSR build ----------------
__global__ __launch_bounds__(256) void hist_k(const int* __restrict__ ei, int* __restrict__ deg) {
    int i = blockIdx.x * 256 + threadIdx.x;
    if (i < N_EDGES) atomicAdd(&deg[ei[N_EDGES + i]], 1);
}

__global__ __launch_bounds__(256) void scanA(const int* __restrict__ deg,
                                             int* __restrict__ excl, int* __restrict__ bsum) {
    __shared__ int s[256];
    int t = threadIdx.x;
    int n = blockIdx.x * 256 + t;
    int v = deg[n];
    s[t] = v;
    __syncthreads();
    for (int off = 1; off < 256; off <<= 1) {
        int tmp = (t >= off) ? s[t - off] : 0;
        __syncthreads();
        s[t] += tmp;
        __syncthreads();
    }
    excl[n] = s[t] - v;
    if (t == 255) bsum[blockIdx.x] = s[255];
}

__global__ __launch_bounds__(512) void scanB(const int* __restrict__ bsum, int* __restrict__ boff) {
    __shared__ int s[512];
    int t = threadIdx.x;
    int v = (t < 400) ? bsum[t] : 0;
    s[t] = v;
    __syncthreads();
    for (int off = 1; off < 512; off <<= 1) {
        int tmp = (t >= off) ? s[t - off] : 0;
        __syncthreads();
        s[t] += tmp;
        __syncthreads();
    }
    if (t < 400) boff[t] = s[t] - v;
}

__global__ __launch_bounds__(256) void scanC(int* __restrict__ row_ptr, const int* __restrict__ boff,
                                             int* __restrict__ cursor) {
    int n = blockIdx.x * 256 + threadIdx.x;
    int v = row_ptr[n] + boff[blockIdx.x];
    row_ptr[n] = v;
    cursor[n] = v;
}

__global__ __launch_bounds__(256) void scatter_k(const int* __restrict__ ei,
                                                 int* __restrict__ cursor, int* __restrict__ col) {
    int i = blockIdx.x * 256 + threadIdx.x;
    if (i < N_EDGES) {
        int d = ei[N_EDGES + i];
        int pos = atomicAdd(&cursor[d], 1);
        col[pos] = ei[i];
    }
}

// ---- wa[k][o] : o<4 -> W1[:,h,:]@a_src1[h], o>=4 -> @a_dst1[h-4]  (64x8) ----
__global__ __launch_bounds__(512) void wa_k(
    const float* __restrict__ W1, const float* __restrict__ a_src,
    const float* __restrict__ a_dst, float* __restrict__ wa)
{
    int t = threadIdx.x;
    int k = t >> 3, o = t & 7;
    int h = o & 3;
    const float* a = (o < 4) ? a_src : a_dst;
    float s = 0.f;
#pragma unroll
    for (int c = 0; c < C1; ++c) s += W1[k * F_MID + h * C1 + c] * a[h * C1 + c];
    wa[k * 8 + o] = s;
}

// ---- al1 = x @ wa  (fp32 logits), and xh = bf16(x) packed table ----
__global__ __launch_bounds__(256) void al1_k(
    const float* __restrict__ x, const float* __restrict__ wa,
    float* __restrict__ al1, unsigned short* __restrict__ xh)
{
    __shared__ float xs[32][65];
    __shared__ float was[64][8];
    int t = threadIdx.x;
    int n0 = blockIdx.x * 32;
#pragma unroll
    for (int j = 0; j < 8; ++j) {
        int idx = t + 256 * j;
        float v = x[(size_t)n0 * F_IN + idx];
        xs[idx >> 6][idx & 63] = v;
        xh[(size_t)n0 * F_IN + idx] = f2bf(v);
    }
    if (t < 128) ((float4*)was)[t] = ((const float4*)wa)[t];
    __syncthreads();
    int nl = t >> 3, o = t & 7;
    float acc = 0.f;
#pragma unroll
    for (int k = 0; k < F_IN; ++k) acc += xs[nl][k] * was[k][o];
    al1[(size_t)(n0 + nl) * 8 + o] = acc;
}

// ---- fused layer-1: one WAVE per dst; bf16 x rows; scalarized edge loop, unroll-8 ----
__global__ __launch_bounds__(256) void gather1(
    const int* __restrict__ row_ptr, const int* __restrict__ row_end,
    const int* __restrict__ col, const unsigned short* __restrict__ xh,
    const float* __restrict__ al1, const float* __restrict__ W1,
    const float* __restrict__ b1, const float* __restrict__ W2,
    const float* __restrict__ a_src2, const float* __restrict__ a_dst2,
    unsigned short* __restrict__ h2h, float* __restrict__ al_s2, float* __restrict__ al_d2)
{
    __shared__ __align__(16) float agg[4][4][68];   // [dstslot][head][k(+pad)]
    __shared__ float invden[4][4];
    __shared__ __align__(16) float os[4][F_MID];
    __shared__ float hsh[4][C2 + 1];
    int t = threadIdx.x;
    int wv = t >> 6;                 // dst slot (one wave each)
    int lane = t & 63;
    int h = lane >> 4;               // head
    int c = lane & 15;               // uint2 slot: channels [4c,4c+4)
    int d = blockIdx.x * 4 + wv;
    const uint2* x2p = (const uint2*)xh;

    {   // ---------- phase 1: aggregate bf16 x over incoming edges ----------
        float adv = al1[d * 8 + 4 + h];
        float w = __expf(lrelu(al1[d * 8 + h] + adv));       // self loop
        float4 xv = bf2f4(x2p[(size_t)d * 16 + c]);
        float4 acc = make_float4(w * xv.x, w * xv.y, w * xv.z, w * xv.w);
        float den = w;
        int e0 = __builtin_amdgcn_readfirstlane(row_ptr[d]);
        int e1 = __builtin_amdgcn_readfirstlane(row_end[d]);
        int e = e0;
        for (; e + 8 <= e1; e += 8) {
            int s0 = __builtin_amdgcn_readfirstlane(col[e]);
            int s1 = __builtin_amdgcn_readfirstlane(col[e + 1]);
            int s2 = __builtin_amdgcn_readfirstlane(col[e + 2]);
            int s3 = __builtin_amdgcn_readfirstlane(col[e + 3]);
            int s4 = __builtin_amdgcn_readfirstlane(col[e + 4]);
            int s5 = __builtin_amdgcn_readfirstlane(col[e + 5]);
            int s6 = __builtin_amdgcn_readfirstlane(col[e + 6]);
            int s7 = __builtin_amdgcn_readfirstlane(col[e + 7]);
            uint2 p0 = x2p[(size_t)s0 * 16 + c];
            uint2 p1 = x2p[(size_t)s1 * 16 + c];
            uint2 p2 = x2p[(size_t)s2 * 16 + c];
            uint2 p3 = x2p[(size_t)s3 * 16 + c];
            uint2 p4 = x2p[(size_t)s4 * 16 + c];
            uint2 p5 = x2p[(size_t)s5 * 16 + c];
            uint2 p6 = x2p[(size_t)s6 * 16 + c];
            uint2 p7 = x2p[(size_t)s7 * 16 + c];
            float av0 = al1[s0 * 8 + h];
            float av1 = al1[s1 * 8 + h];
            float av2 = al1[s2 * 8 + h];
            float av3 = al1[s3 * 8 + h];
            float av4 = al1[s4 * 8 + h];
            float av5 = al1[s5 * 8 + h];
            float av6 = al1[s6 * 8 + h];
            float av7 = al1[s7 * 8 + h];
            float w0 = __expf(lrelu(av0 + adv));
            float w1 = __expf(lrelu(av1 + adv));
            float w2 = __expf(lrelu(av2 + adv));
            float w3 = __expf(lrelu(av3 + adv));
            float w4 = __expf(lrelu(av4 + adv));
            float w5 = __expf(lrelu(av5 + adv));
            float w6 = __expf(lrelu(av6 + adv));
            float w7 = __expf(lrelu(av7 + adv));
            float4 x0 = bf2f4(p0);
            float4 x1 = bf2f4(p1);
            float4 x2 = bf2f4(p2);
            float4 x3 = bf2f4(p3);
            float4 x4 = bf2f4(p4);
            float4 x5 = bf2f4(p5);
            float4 x6 = bf2f4(p6);
            float4 x7 = bf2f4(p7);
            acc.x += w0 * x0.x + w1 * x1.x + w2 * x2.x + w3 * x3.x
                   + w4 * x4.x + w5 * x5.x + w6 * x6.x + w7 * x7.x;
            acc.y += w0 * x0.y + w1 * x1.y + w2 * x2.y + w3 * x3.y
                   + w4 * x4.y + w5 * x5.y + w6 * x6.y + w7 * x7.y;
            acc.z += w0 * x0.z + w1 * x1.z + w2 * x2.z + w3 * x3.z
                   + w4 * x4.z + w5 * x5.z + w6 * x6.z + w7 * x7.z;
            acc.w += w0 * x0.w + w1 * x1.w + w2 * x2.w + w3 * x3.w
                   + w4 * x4.w + w5 * x5.w + w6 * x6.w + w7 * x7.w;
            den += w0 + w1 + w2 + w3 + w4 + w5 + w6 + w7;
        }
        for (; e < e1; ++e) {
            int s = __builtin_amdgcn_readfirstlane(col[e]);
            float av = al1[s * 8 + h];
            float4 xs = bf2f4(x2p[(size_t)s * 16 + c]);
            float we = __expf(lrelu(av + adv));
            acc.x += we * xs.x; acc.y += we * xs.y;
            acc.z += we * xs.z; acc.w += we * xs.w;
            den += we;
        }
        *(float4*)&agg[wv][h][4 * c] = acc;
        if (c == 0) invden[wv][h] = 1.f / den;
    }
    __syncthreads();
    {   // ---------- phase 2: os = elu(agg @ W1 * invden + b1)  (512 outs, 2/thread) ----------
        int ch = t & 127;            // out channel
        int r0 = t >> 7;             // dsts r0 and r0+2
        int hh = ch >> 5;
        float A0 = 0.f, A1 = 0.f;
#pragma unroll 4
        for (int k = 0; k < F_IN; ++k) {
            float wv1 = W1[k * F_MID + ch];
            A0 += agg[r0][hh][k] * wv1;
            A1 += agg[r0 + 2][hh][k] * wv1;
        }
        float bb = b1[ch];
        os[r0][ch]     = elu(A0 * invden[r0][hh] + bb);
        os[r0 + 2][ch] = elu(A1 * invden[r0 + 2][hh] + bb);
    }
    __syncthreads();
    {   // ---------- phase 3: h2 = os @ W2 (bf16 store), then layer-2 logits ----------
        if (t < 128) {
            int r = t >> 5, ch = t & 31;
            float B = 0.f;
#pragma unroll 4
            for (int k = 0; k < F_MID; ++k) B += os[r][k] * W2[k * C2 + ch];
            h2h[(size_t)(blockIdx.x * 4 + r) * C2 + ch] = f2bf(B);
            hsh[r][ch] = B;
        }
        __syncthreads();
        if (t < 8) {
            int r = t & 3, which = t >> 2;
            const float* a = which ? a_dst2 : a_src2;
            float s = 0.f;
#pragma unroll
            for (int k = 0; k < C2; ++k) s += hsh[r][k] * a[k];
            if (which) al_d2[blockIdx.x * 4 + r] = s;
            else       al_s2[blockIdx.x * 4 + r] = s;
        }
    }
}

// ---- layer-2 gather: one WAVE per dst; lane = rep(8) x cslot(8); edge-parallel
// replicas, shuffle-reduce across reps; writes fp32 out2 row (no pooling here).
__global__ __launch_bounds__(256) void gather2(
    const int* __restrict__ row_ptr, const int* __restrict__ row_end,
    const int* __restrict__ col, const float* __restrict__ al_src,
    const float* __restrict__ al_dst, const unsigned short* __restrict__ h2h,
    const float* __restrict__ b2, float* __restrict__ out2)
{
    int t = threadIdx.x;
    int wv = t >> 6;
    int lane = t & 63;
    int rep = lane >> 3;              // edge replica 0..7
    int c   = lane & 7;               // uint2 slot: channels [4c,4c+4)
    int d = blockIdx.x * 4 + wv;
    const uint2* h2v = (const uint2*)h2h;
    float ad = al_dst[d];
    float4 acc = make_float4(0.f, 0.f, 0.f, 0.f);
    float den = 0.f;
    if (rep == 0) {                   // self loop
        float w = __expf(lrelu(al_src[d] + ad));
        float4 v = bf2f4(h2v[(size_t)d * 8 + c]);
        acc = make_float4(w * v.x, w * v.y, w * v.z, w * v.w);
        den = w;
    }
    int e0 = __builtin_amdgcn_readfirstlane(row_ptr[d]);
    int e1 = __builtin_amdgcn_readfirstlane(row_end[d]);
    for (int e = e0 + rep; e < e1; e += 8) {
        int s = col[e];               // coalesced across reps
        float av = al_src[s];
        uint2 p = h2v[(size_t)s * 8 + c];
        float w = __expf(lrelu(av + ad));
        float4 v = bf2f4(p);
        acc.x += w * v.x; acc.y += w * v.y;
        acc.z += w * v.z; acc.w += w * v.w;
        den += w;
    }
    // reduce across the 8 replicas (lane bits 3..5)
#pragma unroll
    for (int off = 8; off < 64; off <<= 1) {
        acc.x += __shfl_xor(acc.x, off, 64);
        acc.y += __shfl_xor(acc.y, off, 64);
        acc.z += __shfl_xor(acc.z, off, 64);
        acc.w += __shfl_xor(acc.w, off, 64);
        den   += __shfl_xor(den,   off, 64);
    }
    if (rep == 0) {
        float inv = 1.f / den;
        const float4 bv = ((const float4*)b2)[c];
        float4 o = make_float4(elu(acc.x * inv + bv.x), elu(acc.y * inv + bv.y),
                               elu(acc.z * inv + bv.z), elu(acc.w * inv + bv.w));
        *(float4*)&out2[(size_t)d * C2 + 4 * c] = o;
    }
}

// ---- mean-pool: 256 nodes/block (spans <=2 graphs since 400 nodes/graph) ----
__global__ __launch_bounds__(256) void pool_k(
    const float* __restrict__ out2, const int* __restrict__ batch,
    float* __restrict__ pooled)
{
    __shared__ float svA[8][C2];
    __shared__ float svB[8][C2];
    int t = threadIdx.x;
    int r = t >> 5;                   // 0..7
    int c = t & 31;
    int n0 = blockIdx.x * 256;
    int g0 = batch[n0], g1 = batch[n0 + 255];
    int bnd = (g0 + 1) * NODES_PER_G; // first node of g0+1
    float sA = 0.f, sB = 0.f;
#pragma unroll 8
    for (int i = 0; i < 32; ++i) {
        int n = n0 + i * 8 + r;
        float v = out2[(size_t)n * C2 + c];
        if (n < bnd) sA += v; else sB += v;
    }
    svA[r][c] = sA;
    svB[r][c] = sB;
    __syncthreads();
    if (t < 32) {
        float a = 0.f, b = 0.f;
#pragma unroll
        for (int rr = 0; rr < 8; ++rr) { a += svA[rr][t]; b += svB[rr][t]; }
        atomicAdd(&pooled[g0 * C2 + t], a);
        if (g1 != g0) atomicAdd(&pooled[g1 * C2 + t], b);
    }
}

// ---- classifier head: one thread per graph (400 nodes/graph exactly) ----
__global__ __launch_bounds__(256) void head_k(
    const float* __restrict__ pooled, const float* __restrict__ clinical,
    const float* __restrict__ Wc1, const float* __restrict__ bc1,
    const float* __restrict__ Wc2, const float* __restrict__ bc2,
    float* __restrict__ out)
{
    int g = threadIdx.x;
    float fused[C2 + CLIN];
    const float inv = 1.f / (float)NODES_PER_G;
#pragma unroll
    for (int c = 0; c < C2; ++c) fused[c] = pooled[g * C2 + c] * inv;
#pragma unroll
    for (int c = 0; c < CLIN; ++c) fused[C2 + c] = clinical[g * CLIN + c];
    float o = bc2[0];
#pragma unroll
    for (int j = 0; j < 16; ++j) {
        float acc = bc1[j];
#pragma unroll
        for (int k = 0; k < C2 + CLIN; ++k) acc += fused[k] * Wc1[k * 16 + j];
        o += (acc > 0.f ? acc : expm1f(acc)) * Wc2[j];
    }
    out[g] = o;
}

extern "C" void kernel_launch(void* const* d_in, const int* in_sizes, int n_in,
                              void* d_out, int out_size, void* d_ws, size_t ws_size,
                              hipStream_t stream) {
    const float* x        = (const float*)d_in[0];
    const int*   ei       = (const int*)  d_in[1];
    const int*   batch    = (const int*)  d_in[2];
    const float* clinical = (const float*)d_in[3];
    const float* W1       = (const float*)d_in[4];
    const float* a_src1   = (const float*)d_in[5];
    const float* a_dst1   = (const float*)d_in[6];
    const float* b1       = (const float*)d_in[7];
    const float* W2       = (const float*)d_in[8];
    const float* a_src2   = (const float*)d_in[9];
    const float* a_dst2   = (const float*)d_in[10];
    const float* b2       = (const float*)d_in[11];
    const float* Wc1      = (const float*)d_in[12];
    const float* bc1      = (const float*)d_in[13];
    const float* Wc2      = (const float*)d_in[14];
    const float* bc2      = (const float*)d_in[15];
    float* out = (float*)d_out;

    const size_t N = N_NODES;
    float* ws = (float*)d_ws;
    size_t off = 0;
    float* al1    = ws + off; off += N * 8;
    float* al_s2  = ws + off; off += N;
    float* al_d2  = ws + off; off += N;
    float* out2   = ws + off; off += N * C2;
    float* pooled = ws + off; off += (size_t)G_GRAPHS * C2;
    float* wa     = ws + off; off += 512;
    unsigned short* xh  = (unsigned short*)(ws + off); off += N * F_IN / 2;  // bf16 x
    unsigned short* h2h = (unsigned short*)(ws + off); off += N * C2 / 2;    // bf16 h2
    int* deg     = (int*)(ws + off); off += N;
    int* row_ptr = (int*)(ws + off); off += N;
    int* cursor  = (int*)(ws + off); off += N;        // after scatter: row ends
    int* bsum    = (int*)(ws + off); off += 512;
    int* boff    = (int*)(ws + off); off += 512;
    int* col     = (int*)(ws + off); off += N_EDGES;

    hipMemsetAsync(deg, 0, N * sizeof(int), stream);
    hipMemsetAsync(pooled, 0, G_GRAPHS * C2 * sizeof(float), stream);

    // CSR build
    hist_k   <<<(N_EDGES + 255) / 256, 256, 0, stream>>>(ei, deg);
    scanA    <<<N_NODES / 256, 256, 0, stream>>>(deg, row_ptr, bsum);
    scanB    <<<1, 512, 0, stream>>>(bsum, boff);
    scanC    <<<N_NODES / 256, 256, 0, stream>>>(row_ptr, boff, cursor);
    scatter_k<<<(N_EDGES + 255) / 256, 256, 0, stream>>>(ei, cursor, col);

    // layer-1 attention logits + bf16 x table
    wa_k <<<1, 512, 0, stream>>>(W1, a_src1, a_dst1, wa);
    al1_k<<<N_NODES / 32, 256, 0, stream>>>(x, wa, al1, xh);

    // fused layer 1 (+ layer-2 GEMM & logits), one wave per dst, unroll-8
    gather1<<<N_NODES / 4, 256, 0, stream>>>(row_ptr, cursor, col, xh, al1, W1, b1,
                                             W2, a_src2, a_dst2, h2h, al_s2, al_d2);

    // layer 2 gather: wave/dst, edge-parallel replicas
    gather2<<<N_NODES / 4, 256, 0, stream>>>(row_ptr, cursor, col, al_s2, al_d2, h2h,
                                             b2, out2);

    // mean-pool + head
    pool_k<<<N_NODES / 256, 256, 0, stream>>>(out2, batch, pooled);
    head_k<<<1, G_GRAPHS, 0, stream>>>(pooled, clinical, Wc1, bc1, Wc2, bc2, out);
}

// Round 12
// 595.363 us; speedup vs baseline: 1.0325x; 1.0325x over previous
//
#include <hip/hip_runtime.h>
#include <math.h>

#define N_NODES 102400
#define N_EDGES 1638400
#define G_GRAPHS 256
#define F_IN  64
#define H1    4
#define C1    32
#define F_MID 128
#define C2    32
#define CLIN  5
#define NEG   0.2f
#define NODES_PER_G 400

__device__ __forceinline__ float lrelu(float x) { return x > 0.f ? x : NEG * x; }
__device__ __forceinline__ float elu(float x)   { return x > 0.f ? x : expm1f(x); }

__device__ __forceinline__ unsigned short f2bf(float f) {
    unsigned u = __float_as_uint(f);
    u = (u + 0x7fffu + ((u >> 16) & 1u)) >> 16;
    return (unsigned short)u;
}
__device__ __forceinline__ float4 bf2f4(unsigned lo, unsigned hi) {
    return make_float4(__uint_as_float(lo << 16), __uint_as_float(lo & 0xffff0000u),
                       __uint_as_float(hi << 16), __uint_as_float(hi & 0xffff0000u));
}
__device__ __forceinline__ float4 bf2f4v(uint2 p) { return bf2f4(p.x, p.y); }
__device__ __forceinline__ float bperm_f(int srclane, float v) {
    return __uint_as_float((unsigned)__builtin_amdgcn_ds_bpermute(srclane * 4, __float_as_uint(v)));
}
__device__ __forceinline__ unsigned bperm_u(int srclane, unsigned v) {
    return (unsigned)__builtin_amdgcn_ds_bpermute(srclane * 4, (int)v);
}

// ---------------- CSR build ----------------
__global__ __launch_bounds__(256) void hist_k(const int* __restrict__ ei, int* __restrict__ deg) {
    int i = blockIdx.x * 256 + threadIdx.x;
    if (i < N_EDGES) atomicAdd(&deg[ei[N_EDGES + i]], 1);
}

__global__ __launch_bounds__(256) void scanA(const int* __restrict__ deg,
                                             int* __restrict__ excl, int* __restrict__ bsum) {
    __shared__ int s[256];
    int t = threadIdx.x;
    int n = blockIdx.x * 256 + t;
    int v = deg[n];
    s[t] = v;
    __syncthreads();
    for (int off = 1; off < 256; off <<= 1) {
        int tmp = (t >= off) ? s[t - off] : 0;
        __syncthreads();
        s[t] += tmp;
        __syncthreads();
    }
    excl[n] = s[t] - v;
    if (t == 255) bsum[blockIdx.x] = s[255];
}

__global__ __launch_bounds__(512) void scanB(const int* __restrict__ bsum, int* __restrict__ boff) {
    __shared__ int s[512];
    int t = threadIdx.x;
    int v = (t < 400) ? bsum[t] : 0;
    s[t] = v;
    __syncthreads();
    for (int off = 1; off < 512; off <<= 1) {
        int tmp = (t >= off) ? s[t - off] : 0;
        __syncthreads();
        s[t] += tmp;
        __syncthreads();
    }
    if (t < 400) boff[t] = s[t] - v;
}

__global__ __launch_bounds__(256) void scanC(int* __restrict__ row_ptr, const int* __restrict__ boff,
                                             int* __restrict__ cursor) {
    int n = blockIdx.x * 256 + threadIdx.x;
    int v = row_ptr[n] + boff[blockIdx.x];
    row_ptr[n] = v;
    cursor[n] = v;
}

__global__ __launch_bounds__(256) void scatter_k(const int* __restrict__ ei,
                                                 int* __restrict__ cursor, int* __restrict__ col) {
    int i = blockIdx.x * 256 + threadIdx.x;
    if (i < N_EDGES) {
        int d = ei[N_EDGES + i];
        int pos = atomicAdd(&cursor[d], 1);
        col[pos] = ei[i];
    }
}

// ---- wa[k][o] : o<4 -> W1[:,h,:]@a_src1[h], o>=4 -> @a_dst1[h-4]  (64x8) ----
__global__ __launch_bounds__(512) void wa_k(
    const float* __restrict__ W1, const float* __restrict__ a_src,
    const float* __restrict__ a_dst, float* __restrict__ wa)
{
    int t = threadIdx.x;
    int k = t >> 3, o = t & 7;
    int h = o & 3;
    const float* a = (o < 4) ? a_src : a_dst;
    float s = 0.f;
#pragma unroll
    for (int c = 0; c < C1; ++c) s += W1[k * F_MID + h * C1 + c] * a[h * C1 + c];
    wa[k * 8 + o] = s;
}

// ---- al1 = x @ wa  (fp32 logits), and xh = bf16(x) packed table ----
__global__ __launch_bounds__(256) void al1_k(
    const float* __restrict__ x, const float* __restrict__ wa,
    float* __restrict__ al1, unsigned short* __restrict__ xh)
{
    __shared__ float xs[32][65];
    __shared__ float was[64][8];
    int t = threadIdx.x;
    int n0 = blockIdx.x * 32;
#pragma unroll
    for (int j = 0; j < 8; ++j) {
        int idx = t + 256 * j;
        float v = x[(size_t)n0 * F_IN + idx];
        xs[idx >> 6][idx & 63] = v;
        xh[(size_t)n0 * F_IN + idx] = f2bf(v);
    }
    if (t < 128) ((float4*)was)[t] = ((const float4*)wa)[t];
    __syncthreads();
    int nl = t >> 3, o = t & 7;
    float acc = 0.f;
#pragma unroll
    for (int k = 0; k < F_IN; ++k) acc += xs[nl][k] * was[k][o];
    al1[(size_t)(n0 + nl) * 8 + o] = acc;
}

// ---- fused layer-1: one WAVE per dst. Gather role: edge=lane>>3, uint4 slot=lane&7
// (one dwordx4 instruction covers 8 edges at 8 addrs each — TCP addr-throughput is
// the bottleneck, not bytes). Redistribute to accumulation role (head=lane>>4,
// uint2 slot=lane&15) via ds_bpermute. Tail edges padded with w=0 (no serial tail).
__global__ __launch_bounds__(256) void gather1(
    const int* __restrict__ row_ptr, const int* __restrict__ row_end,
    const int* __restrict__ col, const unsigned short* __restrict__ xh,
    const float* __restrict__ al1, const float* __restrict__ W1,
    const float* __restrict__ b1, const float* __restrict__ W2,
    const float* __restrict__ a_src2, const float* __restrict__ a_dst2,
    unsigned short* __restrict__ h2h, float* __restrict__ al_s2, float* __restrict__ al_d2)
{
    __shared__ __align__(16) float agg[4][4][68];   // [dstslot][head][k(+pad)]
    __shared__ float invden[4][4];
    __shared__ __align__(16) float os[4][F_MID];
    __shared__ float hsh[4][C2 + 1];
    int t = threadIdx.x;
    int wv = t >> 6;                 // dst slot (one wave each)
    int lane = t & 63;
    int h = lane >> 4;               // accumulation: head
    int c = lane & 15;               // accumulation: uint2 slot (channels 4c..4c+3)
    int ge = lane >> 3;              // gather: edge replica 0..7
    int gb = lane & 7;               // gather: uint4 slot 0..7
    int d = blockIdx.x * 4 + wv;
    const uint2* x2p = (const uint2*)xh;
    const uint4* x4p = (const uint4*)xh;

    {   // ---------- phase 1 ----------
        float adv = al1[d * 8 + 4 + h];
        float wself = __expf(lrelu(al1[d * 8 + h] + adv));   // self loop
        float4 xv = bf2f4v(x2p[(size_t)d * 16 + c]);
        float4 acc = make_float4(wself * xv.x, wself * xv.y, wself * xv.z, wself * xv.w);
        float den = wself;
        int e0 = __builtin_amdgcn_readfirstlane(row_ptr[d]);
        int e1 = __builtin_amdgcn_readfirstlane(row_end[d]);
        for (int e = e0; e < e1; e += 8) {
            // 8 scalar col indices (col padded by 8 so reads past e1 are safe)
            int s0 = __builtin_amdgcn_readfirstlane(col[e + 0]);
            int s1 = __builtin_amdgcn_readfirstlane(col[e + 1]);
            int s2 = __builtin_amdgcn_readfirstlane(col[e + 2]);
            int s3 = __builtin_amdgcn_readfirstlane(col[e + 3]);
            int s4 = __builtin_amdgcn_readfirstlane(col[e + 4]);
            int s5 = __builtin_amdgcn_readfirstlane(col[e + 5]);
            int s6 = __builtin_amdgcn_readfirstlane(col[e + 6]);
            int s7 = __builtin_amdgcn_readfirstlane(col[e + 7]);
            // select this lane's gather edge; clamp invalid to row 0 (discarded via w=0)
            int sg = s0;
            sg = (ge == 1) ? s1 : sg;
            sg = (ge == 2) ? s2 : sg;
            sg = (ge == 3) ? s3 : sg;
            sg = (ge == 4) ? s4 : sg;
            sg = (ge == 5) ? s5 : sg;
            sg = (ge == 6) ? s6 : sg;
            sg = (ge == 7) ? s7 : sg;
            if (e + ge >= e1) sg = 0;
            // one dwordx4 gather: 8 edges x 8 slots
            uint4 g = x4p[(size_t)sg * 8 + gb];
            // al gather on 32 lanes: lane (ge, gb<4) loads av[edge=ge][head=gb]
            float avg_ = 0.f;
            if (gb < 4) avg_ = al1[(size_t)sg * 8 + gb];
#pragma unroll
            for (int k = 0; k < 8; ++k) {
                // av for (edge k, this lane's head): source lane k*8+h
                float avk = bperm_f(k * 8 + h, avg_);
                float wk = __expf(lrelu(avk + adv));
                if (e + k >= e1) wk = 0.f;                   // scalar cond
                // x uint2 for (edge k, slot c): source lane k*8+(c>>1), half c&1
                int sl = k * 8 + (c >> 1);
                unsigned gx = bperm_u(sl, g.x);
                unsigned gy = bperm_u(sl, g.y);
                unsigned gz = bperm_u(sl, g.z);
                unsigned gw = bperm_u(sl, g.w);
                unsigned lo = (c & 1) ? gz : gx;
                unsigned hi = (c & 1) ? gw : gy;
                float4 xk = bf2f4(lo, hi);
                acc.x += wk * xk.x; acc.y += wk * xk.y;
                acc.z += wk * xk.z; acc.w += wk * xk.w;
                den += wk;
            }
        }
        *(float4*)&agg[wv][h][4 * c] = acc;
        if (c == 0) invden[wv][h] = 1.f / den;
    }
    __syncthreads();
    {   // ---------- phase 2: os = elu(agg @ W1 * invden + b1) ----------
        int ch = t & 127;
        int r0 = t >> 7;
        int hh = ch >> 5;
        float A0 = 0.f, A1 = 0.f;
#pragma unroll 4
        for (int k = 0; k < F_IN; ++k) {
            float wv1 = W1[k * F_MID + ch];
            A0 += agg[r0][hh][k] * wv1;
            A1 += agg[r0 + 2][hh][k] * wv1;
        }
        float bb = b1[ch];
        os[r0][ch]     = elu(A0 * invden[r0][hh] + bb);
        os[r0 + 2][ch] = elu(A1 * invden[r0 + 2][hh] + bb);
    }
    __syncthreads();
    {   // ---------- phase 3: h2 = os @ W2 (bf16 store), then layer-2 logits ----------
        if (t < 128) {
            int r = t >> 5, ch = t & 31;
            float B = 0.f;
#pragma unroll 4
            for (int k = 0; k < F_MID; ++k) B += os[r][k] * W2[k * C2 + ch];
            h2h[(size_t)(blockIdx.x * 4 + r) * C2 + ch] = f2bf(B);
            hsh[r][ch] = B;
        }
        __syncthreads();
        if (t < 8) {
            int r = t & 3, which = t >> 2;
            const float* a = which ? a_dst2 : a_src2;
            float s = 0.f;
#pragma unroll
            for (int k = 0; k < C2; ++k) s += hsh[r][k] * a[k];
            if (which) al_d2[blockIdx.x * 4 + r] = s;
            else       al_s2[blockIdx.x * 4 + r] = s;
        }
    }
}

// ---- layer-2 gather: one WAVE per dst; lane = rep(8) x cslot(8); edge-parallel
// replicas, shuffle-reduce across reps; writes fp32 out2 row.
__global__ __launch_bounds__(256) void gather2(
    const int* __restrict__ row_ptr, const int* __restrict__ row_end,
    const int* __restrict__ col, const float* __restrict__ al_src,
    const float* __restrict__ al_dst, const unsigned short* __restrict__ h2h,
    const float* __restrict__ b2, float* __restrict__ out2)
{
    int t = threadIdx.x;
    int wv = t >> 6;
    int lane = t & 63;
    int rep = lane >> 3;              // edge replica 0..7
    int c   = lane & 7;               // uint2 slot: channels [4c,4c+4)
    int d = blockIdx.x * 4 + wv;
    const uint2* h2v = (const uint2*)h2h;
    float ad = al_dst[d];
    float4 acc = make_float4(0.f, 0.f, 0.f, 0.f);
    float den = 0.f;
    if (rep == 0) {                   // self loop
        float w = __expf(lrelu(al_src[d] + ad));
        float4 v = bf2f4v(h2v[(size_t)d * 8 + c]);
        acc = make_float4(w * v.x, w * v.y, w * v.z, w * v.w);
        den = w;
    }
    int e0 = __builtin_amdgcn_readfirstlane(row_ptr[d]);
    int e1 = __builtin_amdgcn_readfirstlane(row_end[d]);
    for (int e = e0 + rep; e < e1; e += 8) {
        int s = col[e];               // coalesced across reps
        float av = al_src[s];
        uint2 p = h2v[(size_t)s * 8 + c];
        float w = __expf(lrelu(av + ad));
        float4 v = bf2f4v(p);
        acc.x += w * v.x; acc.y += w * v.y;
        acc.z += w * v.z; acc.w += w * v.w;
        den += w;
    }
#pragma unroll
    for (int off = 8; off < 64; off <<= 1) {
        acc.x += __shfl_xor(acc.x, off, 64);
        acc.y += __shfl_xor(acc.y, off, 64);
        acc.z += __shfl_xor(acc.z, off, 64);
        acc.w += __shfl_xor(acc.w, off, 64);
        den   += __shfl_xor(den,   off, 64);
    }
    if (rep == 0) {
        float inv = 1.f / den;
        const float4 bv = ((const float4*)b2)[c];
        float4 o = make_float4(elu(acc.x * inv + bv.x), elu(acc.y * inv + bv.y),
                               elu(acc.z * inv + bv.z), elu(acc.w * inv + bv.w));
        *(float4*)&out2[(size_t)d * C2 + 4 * c] = o;
    }
}

// ---- mean-pool: 256 nodes/block (spans <=2 graphs since 400 nodes/graph) ----
__global__ __launch_bounds__(256) void pool_k(
    const float* __restrict__ out2, const int* __restrict__ batch,
    float* __restrict__ pooled)
{
    __shared__ float svA[8][C2];
    __shared__ float svB[8][C2];
    int t = threadIdx.x;
    int r = t >> 5;
    int c = t & 31;
    int n0 = blockIdx.x * 256;
    int g0 = batch[n0], g1 = batch[n0 + 255];
    int bnd = (g0 + 1) * NODES_PER_G;
    float sA = 0.f, sB = 0.f;
#pragma unroll 8
    for (int i = 0; i < 32; ++i) {
        int n = n0 + i * 8 + r;
        float v = out2[(size_t)n * C2 + c];
        if (n < bnd) sA += v; else sB += v;
    }
    svA[r][c] = sA;
    svB[r][c] = sB;
    __syncthreads();
    if (t < 32) {
        float a = 0.f, b = 0.f;
#pragma unroll
        for (int rr = 0; rr < 8; ++rr) { a += svA[rr][t]; b += svB[rr][t]; }
        atomicAdd(&pooled[g0 * C2 + t], a);
        if (g1 != g0) atomicAdd(&pooled[g1 * C2 + t], b);
    }
}

// ---- classifier head: one thread per graph (400 nodes/graph exactly) ----
__global__ __launch_bounds__(256) void head_k(
    const float* __restrict__ pooled, const float* __restrict__ clinical,
    const float* __restrict__ Wc1, const float* __restrict__ bc1,
    const float* __restrict__ Wc2, const float* __restrict__ bc2,
    float* __restrict__ out)
{
    int g = threadIdx.x;
    float fused[C2 + CLIN];
    const float inv = 1.f / (float)NODES_PER_G;
#pragma unroll
    for (int c = 0; c < C2; ++c) fused[c] = pooled[g * C2 + c] * inv;
#pragma unroll
    for (int c = 0; c < CLIN; ++c) fused[C2 + c] = clinical[g * CLIN + c];
    float o = bc2[0];
#pragma unroll
    for (int j = 0; j < 16; ++j) {
        float acc = bc1[j];
#pragma unroll
        for (int k = 0; k < C2 + CLIN; ++k) acc += fused[k] * Wc1[k * 16 + j];
        o += (acc > 0.f ? acc : expm1f(acc)) * Wc2[j];
    }
    out[g] = o;
}

extern "C" void kernel_launch(void* const* d_in, const int* in_sizes, int n_in,
                              void* d_out, int out_size, void* d_ws, size_t ws_size,
                              hipStream_t stream) {
    const float* x        = (const float*)d_in[0];
    const int*   ei       = (const int*)  d_in[1];
    const int*   batch    = (const int*)  d_in[2];
    const float* clinical = (const float*)d_in[3];
    const float* W1       = (const float*)d_in[4];
    const float* a_src1   = (const float*)d_in[5];
    const float* a_dst1   = (const float*)d_in[6];
    const float* b1       = (const float*)d_in[7];
    const float* W2       = (const float*)d_in[8];
    const float* a_src2   = (const float*)d_in[9];
    const float* a_dst2   = (const float*)d_in[10];
    const float* b2       = (const float*)d_in[11];
    const float* Wc1      = (const float*)d_in[12];
    const float* bc1      = (const float*)d_in[13];
    const float* Wc2      = (const float*)d_in[14];
    const float* bc2      = (const float*)d_in[15];
    float* out = (float*)d_out;

    const size_t N = N_NODES;
    float* ws = (float*)d_ws;
    size_t off = 0;
    float* al1    = ws + off; off += N * 8;
    float* al_s2  = ws + off; off += N;
    float* al_d2  = ws + off; off += N;
    float* out2   = ws + off; off += N * C2;
    float* pooled = ws + off; off += (size_t)G_GRAPHS * C2;
    float* wa     = ws + off; off += 512;
    unsigned short* xh  = (unsigned short*)(ws + off); off += N * F_IN / 2;  // bf16 x
    unsigned short* h2h = (unsigned short*)(ws + off); off += N * C2 / 2;    // bf16 h2
    int* deg     = (int*)(ws + off); off += N;
    int* row_ptr = (int*)(ws + off); off += N;
    int* cursor  = (int*)(ws + off); off += N;        // after scatter: row ends
    int* bsum    = (int*)(ws + off); off += 512;
    int* boff    = (int*)(ws + off); off += 512;
    int* col     = (int*)(ws + off); off += N_EDGES + 8;   // +8: padded tail reads

    hipMemsetAsync(deg, 0, N * sizeof(int), stream);
    hipMemsetAsync(col + N_EDGES, 0, 8 * sizeof(int), stream);
    hipMemsetAsync(pooled, 0, G_GRAPHS * C2 * sizeof(float), stream);

    // CSR build
    hist_k   <<<(N_EDGES + 255) / 256, 256, 0, stream>>>(ei, deg);
    scanA    <<<N_NODES / 256, 256, 0, stream>>>(deg, row_ptr, bsum);
    scanB    <<<1, 512, 0, stream>>>(bsum, boff);
    scanC    <<<N_NODES / 256, 256, 0, stream>>>(row_ptr, boff, cursor);
    scatter_k<<<(N_EDGES + 255) / 256, 256, 0, stream>>>(ei, cursor, col);

    // layer-1 attention logits + bf16 x table
    wa_k <<<1, 512, 0, stream>>>(W1, a_src1, a_dst1, wa);
    al1_k<<<N_NODES / 32, 256, 0, stream>>>(x, wa, al1, xh);

    // fused layer 1 (+ layer-2 GEMM & logits): wave/dst, 8-edge gather groups
    gather1<<<N_NODES / 4, 256, 0, stream>>>(row_ptr, cursor, col, xh, al1, W1, b1,
                                             W2, a_src2, a_dst2, h2h, al_s2, al_d2);

    // layer 2 gather: wave/dst, edge-parallel replicas
    gather2<<<N_NODES / 4, 256, 0, stream>>>(row_ptr, cursor, col, al_s2, al_d2, h2h,
                                             b2, out2);

    // mean-pool + head
    pool_k<<<N_NODES / 256, 256, 0, stream>>>(out2, batch, pooled);
    head_k<<<1, G_GRAPHS, 0, stream>>>(pooled, clinical, Wc1, bc1, Wc2, bc2, out);
}